// Round 8
// baseline (220.225 us; speedup 1.0000x reference)
//
#include <hip/hip_runtime.h>

#define NB   64
#define NT   256
#define NI   512
#define NO   512
#define NOBS 128
#define ETA  0.01f

typedef __attribute__((ext_vector_type(8))) short bf16x8;
typedef __attribute__((ext_vector_type(4))) float f32x4;

__device__ __forceinline__ unsigned short f2bf(float f) {
    unsigned int u = __float_as_uint(f);
    return (unsigned short)((u + 0x7fffu + ((u >> 16) & 1u)) >> 16); // RNE
}

__device__ __forceinline__ bf16x8 cvt8(const float4 a, const float4 b) {
    bf16x8 r;
    r[0] = (short)f2bf(a.x); r[1] = (short)f2bf(a.y);
    r[2] = (short)f2bf(a.z); r[3] = (short)f2bf(a.w);
    r[4] = (short)f2bf(b.x); r[5] = (short)f2bf(b.y);
    r[6] = (short)f2bf(b.z); r[7] = (short)f2bf(b.w);
    return r;
}

// ---------------- K1: fused convert+gather + LDS-tiled bf16 MFMA GEMM ----------
// 6 blocks/batch: sub 0..3 -> G 128-blocks (bm=sub>>1,bn=sub&1) [full G]
//                 sub 4..5 -> P0 row-blocks {0,1}
// Staging converts fp32 global -> bf16 LDS on the fly (RNE, same as old k0).
__global__ __launch_bounds__(256)
void k1_gemm(const float* __restrict__ X, const float* __restrict__ Wi,
             const int* __restrict__ obs,
             float* __restrict__ G, float* __restrict__ P0)
{
    __shared__ unsigned short As[128 * 64];
    __shared__ unsigned short Bs[128 * 64];

    const int tid  = threadIdx.x;
    const int lane = tid & 63;
    const int wv   = tid >> 6;
    const int l16  = lane & 15;
    const int quad = lane >> 4;

    const int b   = blockIdx.x & 63;      // same-batch blocks -> same XCD
    const int sub = blockIdx.x >> 6;      // 0..5

    const float* xbB = X + (size_t)b * NT * NI;
    const float *aBase, *bBase;
    int bGather = 0;
    float* outp;
    int ldo;
    if (sub < 4) {
        const int bm = sub >> 1, bn = sub & 1;
        aBase = xbB + (size_t)bm * 128 * NI;
        bBase = xbB + (size_t)bn * 128 * NI;
        outp  = G + (size_t)b * NT * NT + (size_t)bm * 128 * NT + bn * 128;
        ldo   = NT;
    } else {
        const int pb = sub - 4;
        aBase = xbB + (size_t)pb * 128 * NI;
        bBase = Wi + (size_t)b * NO * NI;   // gathered via obs
        bGather = 1;
        outp  = P0 + (size_t)b * NT * NOBS + (size_t)pb * 128 * NOBS;
        ldo   = NOBS;
    }

    const int wm = (wv >> 1) * 64;
    const int wn = (wv & 1) * 64;

    f32x4 acc[4][4] = {};

    for (int kb = 0; kb < NI / 64; ++kb) {
        __syncthreads();
        // ---- stage both 128x64 bf16 tiles (fp32->bf16 convert in flight) ----
#pragma unroll
        for (int it = 0; it < 4; ++it) {
            const int s = it * 256 + tid;          // slot id 0..1023
            const int m = s >> 3, c = s & 7;
            const int slot = m * 64 + ((c ^ (m & 7)) * 8);
            const size_t aoff = (size_t)m * NI + kb * 64 + c * 8;
            const float4* ap = (const float4*)(aBase + aoff);
            *(bf16x8*)&As[slot] = cvt8(ap[0], ap[1]);
            const size_t brow = bGather ? (size_t)obs[m] * NI : (size_t)m * NI;
            const float4* bp = (const float4*)(bBase + brow + kb * 64 + c * 8);
            *(bf16x8*)&Bs[slot] = cvt8(bp[0], bp[1]);
        }
        __syncthreads();
#pragma unroll
        for (int ks = 0; ks < 2; ++ks) {
            const int q = ks * 4 + quad;
            bf16x8 af[4], bfr[4];
#pragma unroll
            for (int mt = 0; mt < 4; ++mt) {
                const int m = wm + mt * 16 + l16;
                af[mt] = *(const bf16x8*)&As[m * 64 + ((q ^ (m & 7)) * 8)];
            }
#pragma unroll
            for (int nt = 0; nt < 4; ++nt) {
                const int n = wn + nt * 16 + l16;
                bfr[nt] = *(const bf16x8*)&Bs[n * 64 + ((q ^ (n & 7)) * 8)];
            }
#pragma unroll
            for (int mt = 0; mt < 4; ++mt)
#pragma unroll
                for (int nt = 0; nt < 4; ++nt)
                    acc[mt][nt] = __builtin_amdgcn_mfma_f32_16x16x32_bf16(
                        af[mt], bfr[nt], acc[mt][nt], 0, 0, 0);
        }
    }

#pragma unroll
    for (int mt = 0; mt < 4; ++mt)
#pragma unroll
        for (int nt = 0; nt < 4; ++nt)
#pragma unroll
            for (int r = 0; r < 4; ++r)
                outp[(size_t)(wm + mt * 16 + quad * 4 + r) * ldo
                     + wn + nt * 16 + l16] = acc[mt][nt][r];
}

// ---------------- K2: scan, wave-per-row updates w/ scalar G loads ----------------
// block = (b, 64 j's) -> 128 blocks, 512 threads (8 waves), lane = j.
// preL[256][64] in LDS. Per chunk c:
//  P1: wave0 = serial 16 sigmoid steps (gdiag LDS, ping-pong);
//      waves 1-7 lazy-apply Y_{c-1} to rows >= 16c+32 (G row uniform -> s_load)
//  P2: all waves eager-apply Y_c to rows 16c+16..16c+47.
__global__ __launch_bounds__(512)
void k2_scan(const float* __restrict__ G, const float* __restrict__ P0,
             float* __restrict__ out)
{
    __shared__ float preL[256 * 64];       // 64 KB [t][j]
    __shared__ float gdiag[16 * 16 * 16];  // 16 KB [c][u][v]
    __shared__ float yb[2][16 * 64];       //  8 KB ping-pong y

    const int tid = threadIdx.x;
    const int j   = tid & 63;
    const int wvu = __builtin_amdgcn_readfirstlane(tid >> 6);  // uniform wave id

    const int b  = blockIdx.x & 63;        // same-batch blocks -> same XCD
    const int jb = blockIdx.x >> 6;        // 0..1

    const float* Gb = G  + (size_t)b * NT * NT;
    const float* Pb = P0 + (size_t)b * NT * NOBS + jb * 64;
    float*       ob = out + (size_t)b * NT * NOBS + jb * 64;

    // ---- init: P0 -> preL ; G diag 16-blocks -> gdiag ----
#pragma unroll
    for (int p = 0; p < 8; ++p) {
        const int i = p * 512 + tid;       // 4096 f32x4
        const int row = i >> 4, q = i & 15;
        ((f32x4*)preL)[i] = *(const f32x4*)(Pb + (size_t)row * NOBS + q * 4);
    }
#pragma unroll
    for (int p = 0; p < 2; ++p) {
        const int fi = p * 512 + tid;      // 1024 f32x4
        const int c = fi >> 6, u = (fi >> 2) & 15, v4 = fi & 3;
        ((f32x4*)gdiag)[fi] =
            *(const f32x4*)(Gb + (size_t)(c * 16 + u) * NT + c * 16 + v4 * 4);
    }
    __syncthreads();

    for (int c = 0; c < 16; ++c) {
        const int cp = c & 1;
        // ---------------- P1 ----------------
        if (wvu == 0) {
            // serial phase: 16 sigmoid steps for 64 j's (lane = j)
            float pre[16];
#pragma unroll
            for (int u = 0; u < 16; ++u) pre[u] = preL[(c * 16 + u) * 64 + j];
            const float* gd = gdiag + c * 256;
            f32x4 r0[4], r1[4];
#pragma unroll
            for (int q = 0; q < 4; ++q) r0[q] = ((const f32x4*)gd)[q];
#pragma unroll
            for (int q = 0; q < 4; ++q) r1[q] = ((const f32x4*)(gd + 16))[q];
#pragma unroll
            for (int u = 0; u < 16; ++u) {
                const float y = 1.f / (1.f + __expf(-pre[u]));
                yb[cp][u * 64 + j] = y;
                ob[(size_t)(c * 16 + u) * NOBS + j] = y;
                const float e = ETA * y;
                const float* g = (const float*)((u & 1) ? r1 : r0);
#pragma unroll
                for (int v = 0; v < 16; ++v)
                    if (v > u) pre[v] = fmaf(e, g[v], pre[v]);
                if (u + 2 < 16) {
                    f32x4* tgt = (u & 1) ? r1 : r0;
#pragma unroll
                    for (int q = 0; q < 4; ++q)
                        tgt[q] = ((const f32x4*)(gd + (u + 2) * 16))[q];
                }
            }
        } else if (c >= 1) {
            // lazy: waves 1-7 apply Y_{c-1} to rows >= 16c+32
            float ey[16];
#pragma unroll
            for (int u = 0; u < 16; ++u) ey[u] = ETA * yb[cp ^ 1][u * 64 + j];
            const int kcol = (c - 1) * 16;
            const float* gcol = Gb + kcol;
#pragma unroll 2
            for (int t = c * 16 + 32 + (wvu - 1); t < NT; t += 7) {
                const float* gr = gcol + (size_t)t * NT;   // wave-uniform addr
                float gv[16];
#pragma unroll
                for (int u = 0; u < 16; ++u) gv[u] = gr[u];
                float acc = preL[t * 64 + j];
#pragma unroll
                for (int u = 0; u < 16; ++u) acc = fmaf(ey[u], gv[u], acc);
                preL[t * 64 + j] = acc;
            }
        }
        __syncthreads();
        // ---------------- P2: eager Y_c -> rows 16c+16 .. 16c+47 ----------------
        {
            float ey[16];
#pragma unroll
            for (int u = 0; u < 16; ++u) ey[u] = ETA * yb[cp][u * 64 + j];
            const int kcol = c * 16;
            const float* gcol = Gb + kcol;
            const int tend = (c * 16 + 48 < NT) ? c * 16 + 48 : NT;
#pragma unroll 2
            for (int t = c * 16 + 16 + wvu; t < tend; t += 8) {
                const float* gr = gcol + (size_t)t * NT;   // wave-uniform addr
                float gv[16];
#pragma unroll
                for (int u = 0; u < 16; ++u) gv[u] = gr[u];
                float acc = preL[t * 64 + j];
#pragma unroll
                for (int u = 0; u < 16; ++u) acc = fmaf(ey[u], gv[u], acc);
                preL[t * 64 + j] = acc;
            }
        }
        __syncthreads();
    }
}

extern "C" void kernel_launch(void* const* d_in, const int* in_sizes, int n_in,
                              void* d_out, int out_size, void* d_ws, size_t ws_size,
                              hipStream_t stream)
{
    const float* X   = (const float*)d_in[0];
    const float* Wi  = (const float*)d_in[1];
    const int*   obs = (const int*)d_in[2];
    float*       out = (float*)d_out;

    float* G  = (float*)d_ws;                           // 16 MB
    float* P0 = (float*)((char*)d_ws + (16u << 20));    //  8 MB

    hipLaunchKernelGGL(k1_gemm, dim3(NB * 6), dim3(256), 0, stream,
                       X, Wi, obs, G, P0);
    hipLaunchKernelGGL(k2_scan, dim3(NB * 2), dim3(512), 0, stream,
                       G, P0, out);
}